// Round 9
// baseline (152.390 us; speedup 1.0000x reference)
//
#include <hip/hip_runtime.h>

// Smoother: out = max(pred, (reflect-pad moving-sum(K=501) + bias)/K)
// pred: [B=8, T=16384, C=128] fp32.
// Round 9: private per-lane window sums (NO cross-lane ops in the inner
// loop -- r8's shuffle chain was the wall), CHN=8 ring (34 KB) -> 4
// blocks/CU, 64-row shadow so inner-loop LDS reads are immediate-offset
// (ds_read2-mergeable), global_load_lds staging, nontemporal stores.

constexpr int B    = 8;
constexpr int T    = 16384;
constexpr int C    = 128;
constexpr int K    = 501;
constexpr int CHN  = 8;               // channels per block
constexpr int NSEG = 8;               // segments per column
constexpr int SEGR = T / NSEG;        // 2048 output rows per block
constexpr int RING = 1024;            // main ring rows (pow2)
constexpr int SHAD = 64;              // shadow rows (dup of phases 0..63)
constexpr int CHK  = 64;              // staging chunk rows
constexpr int PRO  = 12;              // prologue chunks (stage-ahead depth)
constexpr int NC   = 40;              // total chunks: rows jstart..jstart+2559

__device__ __forceinline__ int ridx(int j) {
    j = (j < 0) ? -j : j;
    return (j >= T) ? (2 * T - 2 - j) : j;
}

__device__ __forceinline__ void dma16(const float* g, float* l) {
    __builtin_amdgcn_global_load_lds(
        (const __attribute__((address_space(1))) void*)g,
        (__attribute__((address_space(3))) void*)l, 16, 0, 0);
}
__device__ __forceinline__ void dma4(const float* g, float* l) {
    __builtin_amdgcn_global_load_lds(
        (const __attribute__((address_space(1))) void*)g,
        (__attribute__((address_space(3))) void*)l, 4, 0, 0);
}

__global__ __launch_bounds__(64, 1) void smoother_kernel(
    const float* __restrict__ pred, const float* __restrict__ bias,
    float* __restrict__ out) {
    __shared__ float ring[(RING + SHAD) * CHN];   // 8704 floats = 34816 B

    // 1024 blocks: b = blockIdx&7 (one batch per XCD), cg (16), seg (8).
    const int b   = blockIdx.x & 7;
    const int cg  = (blockIdx.x >> 3) & 15;
    const int seg = blockIdx.x >> 7;
    const int g0  = seg * SEGR;
    const int jstart = g0 - 256;          // ring phase 0 = row jstart

    const int lane = threadIdx.x & 63;
    const int o    = lane >> 3;           // row offset 0..7
    const int ch   = lane & 7;            // channel within group

    const float* pb = pred + (size_t)b * T * C + cg * CHN;

    // ---- stage chunk m (64 rows) into ring phase (m*64)&1023; if that
    // phase is 0, duplicate into the shadow region too ----
    auto writeChunk = [&](int j0, int tp) {   // tp = target phase
        if (j0 >= 0 && j0 + CHK <= T) {
            #pragma unroll
            for (int i = 0; i < 2; ++i) {
                const float* g = pb + (size_t)(j0 + 32 * i + (lane >> 1)) * C
                               + (lane & 1) * 4;
                dma16(g, &ring[(tp + 32 * i) * CHN]);
            }
        } else {
            #pragma unroll
            for (int i = 0; i < 8; ++i) {
                const int jr = ridx(j0 + 8 * i + (lane >> 3));
                dma4(pb + (size_t)jr * C + (lane & 7),
                     &ring[(tp + 8 * i) * CHN]);
            }
        }
    };
    auto stage = [&](int m) {
        const int ph0 = (m * CHK) & (RING - 1);
        const int j0  = jstart + m * CHK;
        writeChunk(j0, ph0);
        if (ph0 == 0) writeChunk(j0, RING);   // shadow dup (rows 0..63)
    };

    // ---- prologue ----
    for (int m = 0; m < PRO; ++m) stage(m);

    const float rk  = 1.0f / (float)K;
    const float brk = bias[0] * rk;

    // ---- seed: S_o = sum rows [g0+o-250, g0+o+250] (phases 6..513) ----
    // cooperative: each o-lane sums a stride-8 comb, butterfly over o,
    // then per-lane edge adjust.
    float acc = 0.f;
    for (int i = 6 + o; i <= 506; i += 8)
        acc += ring[i * CHN + ch];
    acc += __shfl_xor(acc, 8);
    acc += __shfl_xor(acc, 16);
    acc += __shfl_xor(acc, 32);            // acc = S(g0), all lanes, per ch
    float S = acc;
    #pragma unroll
    for (int i = 1; i < 8; ++i) {
        const float e = ring[(506 + i) * CHN + ch] - ring[(5 + i) * CHN + ch];
        S += (i <= o) ? e : 0.f;
    }

    // ---- slide: 32 chunks x 8 steps; each step = 8 rows x 8 ch ----
    // lane (o,ch): rows t = tb+o; S += sum(x[t+251..t+258]) - sum(x[t-250..t-243])
    int iN = (507 + o) * CHN + ch;    // base float-idx, new group
    int iO = (6   + o) * CHN + ch;    // old group
    int iC = (256 + o) * CHN + ch;    // center
    float* op = out + (size_t)b * T * C + (size_t)(g0 + o) * C + cg * CHN + ch;

    int ms = PRO;
    for (int k = 0; k < SEGR / CHK; ++k) {        // 32 iterations
        #pragma unroll
        for (int i2 = 0; i2 < CHK / 8; ++i2) {    // 8 steps
            const int off = i2 * 64;
            float d = 0.f;
            #pragma unroll
            for (int j = 0; j < 8; ++j)
                d += ring[iN + off + 8 * j] - ring[iO + off + 8 * j];
            const float vc = ring[iC + off];
            const float sm = fmaf(S, rk, brk);
            __builtin_nontemporal_store(fmaxf(vc, sm), op);
            S += d;
            op += 8 * C;
        }
        // advance bases by one chunk (512 floats = 64 rows); wrap to main ring
        iN += 512; iN = (iN >= RING * CHN) ? iN - RING * CHN : iN;
        iO += 512; iO = (iO >= RING * CHN) ? iO - RING * CHN : iO;
        iC += 512; iC = (iC >= RING * CHN) ? iC - RING * CHN : iC;
        if (ms < NC) { stage(ms); ++ms; }
    }
}

extern "C" void kernel_launch(void* const* d_in, const int* in_sizes, int n_in,
                              void* d_out, int out_size, void* d_ws, size_t ws_size,
                              hipStream_t stream) {
    const float* pred = (const float*)d_in[0];
    const float* bias = (const float*)d_in[1];
    float*       out  = (float*)d_out;

    const int blocks = B * (C / CHN) * NSEG;   // 8 * 16 * 8 = 1024
    smoother_kernel<<<blocks, 64, 0, stream>>>(pred, bias, out);
}